// Round 4
// baseline (246.129 us; speedup 1.0000x reference)
//
#include <hip/hip_runtime.h>

// CropConv on MI355X: mask degenerates to all-True -> pure stride-2 3x3 conv.
// Implicit GEMM: M=COUT=256, N=B*OH*OW=32768, K=CIN*9=2304, f16 MFMA 32x32x16.
//
// R4: occupancy doubled. R1-R3 proved the kernel is latency-bound (all pipes
// <30% busy) at the invariant 2 waves/SIMD. Per-wave tile halved to 64co x 32n
// (18 MFMA/cc, acc=32 VGPR), block = 4 waves = 128co x 2 oh rows, grid 1024 =
// 4 blocks/CU = 4 waves/SIMD. x tile is 5 ih rows (21.2KB LDS double-buffered).
// Weights still global->VGPR direct (R3), kh-grouped to keep live set small.
// __launch_bounds__(256,4) caps VGPR at 128 for 4 waves/SIMD.

#define B_   32
#define CIN  256
#define COUT 256
#define H_   64
#define W_   64
#define OH   32
#define OW   32

typedef _Float16 f16;
typedef _Float16 half8 __attribute__((ext_vector_type(8)));
typedef float    floatx16 __attribute__((ext_vector_type(16)));

// Pre-pass: repack fp32 weights [256][256][3][3] -> f16 in d_ws with layout
// [co_t 2][cc 16][khw 9][co_l 128][ci_l 16]  (1,179,648 B)
__global__ __launch_bounds__(256) void repack_w_kernel(const float* __restrict__ w,
                                                       f16* __restrict__ rp) {
  int o = blockIdx.x * 256 + threadIdx.x;     // 589824 total, exact
  int ci_l = o & 15;
  int tt = o >> 4;
  int co_l = tt & 127; tt >>= 7;
  int khw = tt % 9;    tt /= 9;
  int cc   = tt & 15;  tt >>= 4;
  int co_t = tt;                               // 0..1
  int co = co_t * 128 + co_l;
  int ci = cc * 16 + ci_l;
  rp[o] = (f16)w[(co * CIN + ci) * 9 + khw];
}

// Non-draining workgroup barrier: LDS ops flushed, VMEM loads stay in flight.
static __device__ __forceinline__ void wg_barrier() {
  __builtin_amdgcn_sched_barrier(0);
  asm volatile("s_waitcnt lgkmcnt(0)" ::: "memory");
  __builtin_amdgcn_s_barrier();
  __builtin_amdgcn_sched_barrier(0);
}

// LDS x tile, 5 ih rows, even/odd iw planes, double buffered.
// Element (p,r,idx,ci): p*ODD + r*528 + idx*16 + (ci ^ (idx&8))  [ci-half XOR swizzle]
#define PLANE 2640          // 5 * 33 * 16 f16
#define ODD   2648          // PLANE + 8 f16 pad (bank-slot parity)
#define XBUF  5288          // ODD + PLANE f16 per buffer (10576 B)

__global__ __launch_bounds__(256, 4) void conv_mfma_kernel(
    const float* __restrict__ x, const f16* __restrict__ rp,
    float* __restrict__ out) {
  __shared__ __align__(16) f16 xs[2 * XBUF];   // 21152 B

  const int t    = threadIdx.x;
  const int lane = t & 63;
  const int wave = t >> 6;
  const int wm   = wave >> 1;   // co 64-half within 128
  const int wn   = wave & 1;    // oh row within pair

  const int blk  = blockIdx.x;  // 1024 = b(32) x co_t(2) x ohp(16)
  const int b    = blk >> 5;
  const int rem  = blk & 31;
  const int co_t = rem >> 4;
  const int ohp  = rem & 15;
  const int oh0  = ohp << 1;
  const int ih0  = (ohp << 2) - 1;             // ih rows ih0..ih0+4

  const float* xb = x + (size_t)b * CIN * H_ * W_;

  // staging map: thread -> (iw, ci-half g_st, row-half rh). rh wave-uniform:
  // waves 0,1 stage rows 0-2; waves 2,3 stage rows 3,4.
  const int iw    = t & 63;
  const int g_st  = (t >> 6) & 1;
  const int rbase = __builtin_amdgcn_readfirstlane(t >> 7) * 3;   // 0 or 3
  const int k0 = (lane >> 5) * 8;
  const int ml = lane & 31;
  const int p_st   = iw & 1;
  const int idx_st = (iw + p_st) >> 1;
  const int gx     = (idx_st >> 3) & 1;        // write-side ci-half XOR

  f16* const xs0 = xs;
  f16* const xs1 = xs + XBUF;

  // per-lane A-fragment base in repacked weights (coalesced 1KB wave loads)
  const f16* const AbL = rp + (size_t)co_t * (16 * 9 * 128 * 16)
                            + (wm * 64 + ml) * 16 + k0;

  floatx16 acc[2];
#pragma unroll
  for (int mi = 0; mi < 2; ++mi)
#pragma unroll
    for (int i = 0; i < 16; ++i) acc[mi][i] = 0.f;

  float xv[3][8];     // staged x rows (rows rbase..rbase+2, 8 ci each)

  auto load_x = [&](const float* bcc) {
#pragma unroll
    for (int it = 0; it < 3; ++it) {
      const int r = rbase + it;
      if (r < 5) {                                   // wave-uniform
        const int ih = ih0 + r;
        if (ih >= 0) {
          const float* p0 = bcc + (size_t)(g_st * 8) * 4096 + (size_t)ih * 64 + iw;
#pragma unroll
          for (int c = 0; c < 8; ++c) xv[it][c] = p0[(size_t)c * 4096];
        } else {
#pragma unroll
          for (int c = 0; c < 8; ++c) xv[it][c] = 0.f;
        }
      }
    }
  };

  auto write_x = [&](f16* xoth) {
    f16* d = xoth + p_st * ODD + idx_st * 16 + (g_st ^ gx) * 8;
#pragma unroll
    for (int it = 0; it < 3; ++it) {
      const int r = rbase + it;
      if (r < 5) {
        half8 v;
#pragma unroll
        for (int c = 0; c < 8; ++c) v[c] = (f16)xv[it][c];
        *(half8*)&d[r * 528] = v;
      }
    }
  };

  auto compute = [&](const f16* Abc, const f16* xcur) {
    // swizzled, lane-constant B read bases; row r = 2*wn + kh
    const f16* Be  = xcur + wn * 1056 + ml * 16 + (k0 ^ (ml & 8));   // even plane
    const f16* Bo1 = Be + ODD;                                       // odd, idx=ml
    const f16* Bo2 = xcur + ODD + wn * 1056 + (ml + 1) * 16 + (k0 ^ ((ml + 1) & 8));
    __builtin_amdgcn_s_setprio(1);
#pragma unroll
    for (int kh = 0; kh < 3; ++kh) {
      // kh-grouped A loads: 6 x 1KB coalesced, small live set (24 VGPR)
      half8 a0[3], a1[3];
#pragma unroll
      for (int kw = 0; kw < 3; ++kw) {
        a0[kw] = *(const half8*)&Abc[(kh * 3 + kw) * 2048];
        a1[kw] = *(const half8*)&Abc[(kh * 3 + kw) * 2048 + 512];
      }
#pragma unroll
      for (int kw = 0; kw < 3; ++kw) {
        const f16* Bp = (kw == 0) ? Bo1 : (kw == 1) ? Be : Bo2;
        half8 bf = *(const half8*)&Bp[kh * 528];
        acc[0] = __builtin_amdgcn_mfma_f32_32x32x16_f16(a0[kw], bf, acc[0], 0, 0, 0);
        acc[1] = __builtin_amdgcn_mfma_f32_32x32x16_f16(a1[kw], bf, acc[1], 0, 0, 0);
      }
    }
    __builtin_amdgcn_s_setprio(0);
  };

  // zero the odd-plane pad column (iw=-1 -> idx 0) of both buffers, once
  if (t < 160) {
    const int bufi = t >= 80;
    const int u = t - bufi * 80;
    const int r = u >> 4, ci = u & 15;
    xs[bufi * XBUF + ODD + r * 528 + ci] = (f16)0.f;
  }

  // prologue: stage cc=0 (latency exposed once); issue cc=1 loads
  load_x(xb);
  write_x(xs0);
  load_x(xb + 65536);
  __syncthreads();   // single full drain, outside the hot loop

  const f16* Abc = AbL;
  f16* curp = xs0;
  f16* othp = xs1;
#pragma unroll 1
  for (int cc = 0; cc < 16; ++cc) {
    compute(Abc, curp);                 // LDS B + global A, MFMA
    Abc += 18432;
    if (cc < 15) {
      write_x(othp);                    // cvt+store cc+1 (loads issued a full cc ago)
      if (cc < 14) load_x(xb + (size_t)(cc + 2) * 65536);
      wg_barrier();                     // publish xs[other]; loads stay in flight
      f16* tm = curp; curp = othp; othp = tm;
    }
  }

  // ---- epilogue: C/D col=lane&31 (=ow), row=(reg&3)+8*(reg>>2)+4*(lane>>5) ----
  const int col = ml;
  const int rowbase = (lane >> 5) * 4;
  const int oh = oh0 + wn;
  float* ob = out + ((size_t)b * COUT + co_t * 128 + wm * 64) * (OH * OW)
                  + (size_t)oh * OW + col;
#pragma unroll
  for (int mi = 0; mi < 2; ++mi) {
#pragma unroll
    for (int r = 0; r < 16; ++r) {
      const int row = mi * 32 + (r & 3) + 8 * (r >> 2) + rowbase;
      ob[(size_t)row * (OH * OW)] = acc[mi][r];
    }
  }
}

extern "C" void kernel_launch(void* const* d_in, const int* in_sizes, int n_in,
                              void* d_out, int out_size, void* d_ws, size_t ws_size,
                              hipStream_t stream) {
  const float* x = (const float*)d_in[0];   // [32][256][64][64] fp32
  const float* w = (const float*)d_in[1];   // [256][256][3][3]  fp32
  float* out = (float*)d_out;               // [32][256][32][32] fp32
  f16* rp = (f16*)d_ws;                     // 1.18 MB repacked f16 weights

  repack_w_kernel<<<2304, 256, 0, stream>>>(w, rp);
  conv_mfma_kernel<<<1024, 256, 0, stream>>>(x, rp, out);
}

// Round 5
// 239.817 us; speedup vs baseline: 1.0263x; 1.0263x over previous
//
#include <hip/hip_runtime.h>

// CropConv on MI355X: mask degenerates to all-True -> pure stride-2 3x3 conv.
// Implicit GEMM: M=COUT=256, N=B*OH*OW=32768, K=CIN*9=2304, f16 MFMA 32x32x16.
//
// R5: BK=32 discriminator. R1-R3 all sit at ~12.6K cyc per K-iteration despite
// different schedules; R4 showed more waves hurts. This round halves the
// iteration count (8 phases of 32 ci) holding total staging work constant:
// if per-iteration overhead dominates -> ~2x faster; if staging throughput
// dominates -> unchanged. Geometry reverted to R3 (512 blocks, 4 waves,
// 64co x 64n per wave). Weights global->VGPR direct (R3), kh-grouped (R4).

#define B_   32
#define CIN  256
#define COUT 256
#define H_   64
#define W_   64
#define OH   32
#define OW   32

typedef _Float16 f16;
typedef _Float16 half8 __attribute__((ext_vector_type(8)));
typedef float    floatx16 __attribute__((ext_vector_type(16)));

// Pre-pass: repack fp32 weights [256][256][3][3] -> f16 in d_ws with layout
// [co_t 2][cc 16][khw 9][co_l 128][ci_l 16]  (1,179,648 B)
__global__ __launch_bounds__(256) void repack_w_kernel(const float* __restrict__ w,
                                                       f16* __restrict__ rp) {
  int o = blockIdx.x * 256 + threadIdx.x;     // 589824 total, exact
  int ci_l = o & 15;
  int tt = o >> 4;
  int co_l = tt & 127; tt >>= 7;
  int khw = tt % 9;    tt /= 9;
  int cc   = tt & 15;  tt >>= 4;
  int co_t = tt;                               // 0..1
  int co = co_t * 128 + co_l;
  int ci = cc * 16 + ci_l;
  rp[o] = (f16)w[(co * CIN + ci) * 9 + khw];
}

// Non-draining workgroup barrier: LDS ops flushed, VMEM loads stay in flight.
static __device__ __forceinline__ void wg_barrier() {
  __builtin_amdgcn_sched_barrier(0);
  asm volatile("s_waitcnt lgkmcnt(0)" ::: "memory");
  __builtin_amdgcn_s_barrier();
  __builtin_amdgcn_sched_barrier(0);
}

// xs: 2 buffers x 2 sub-tiles x 9520 f16. Sub-tile layout (verified R2/R3):
// even plane [0,4752), pad 8, odd plane [4760,9512).
// Element (p,r,idx,ci): p*4760 + r*528 + idx*16 + (ci ^ (idx&8))
#define SUBT  9520
#define XBUF  (2 * SUBT)     // 19040 f16 per buffer (one 32-ci pair)

__global__ __launch_bounds__(256, 2) void conv_mfma_kernel(
    const float* __restrict__ x, const f16* __restrict__ rp,
    float* __restrict__ out) {
  __shared__ __align__(16) f16 xs[2 * XBUF];   // 76160 B

  const int t    = threadIdx.x;
  const int lane = t & 63;
  const int wave = t >> 6;
  const int wm   = wave >> 1;   // co 64-half within 128
  const int wn   = wave & 1;    // n 64-half within 128 (= 2 output rows)

  const int blk  = blockIdx.x;  // 512
  const int b    = blk >> 4;
  const int rem  = blk & 15;
  const int co_t = rem >> 3;
  const int oh0  = (rem & 7) << 2;
  const int ih0  = 2 * oh0 - 1;

  const float* xb = x + (size_t)b * CIN * H_ * W_;

  const int iw  = t & 63;                                  // staging column
  const int rru = __builtin_amdgcn_readfirstlane(t >> 6);  // staging row group
  const int k0  = (lane >> 5) * 8;
  const int ml  = lane & 31;
  const int p_st   = iw & 1;                               // staging plane
  const int idx_st = (iw + p_st) >> 1;                     // staging idx in plane
  const int gx     = (idx_st >> 3) & 1;                    // write-side ci-half XOR

  f16* const xs0 = xs;
  f16* const xs1 = xs + XBUF;

  // per-lane A-fragment base in repacked weights (coalesced 1KB wave loads)
  const f16* const AbL = rp + (size_t)co_t * (16 * 9 * 128 * 16)
                            + (wm * 64 + ml) * 16 + k0;

  floatx16 acc[2][2];
#pragma unroll
  for (int mi = 0; mi < 2; ++mi)
#pragma unroll
    for (int nj = 0; nj < 2; ++nj)
#pragma unroll
      for (int i = 0; i < 16; ++i) acc[mi][nj][i] = 0.f;

  // two register banks = one 32-ci pair of x in flight
  float xva[3][2][8], xvb[3][2][8];

  auto load_x = [&](float (&xv)[3][2][8], int cc16) {
    const float* bcc = xb + (size_t)cc16 * 16 * 4096;
#pragma unroll
    for (int it = 0; it < 3; ++it) {
      const int r = rru + it * 4;                          // wave-uniform
      if (r < 9) {
        const int ih = ih0 + r;
        if (ih >= 0) {
          const float* p0 = bcc + (size_t)ih * 64 + iw;
#pragma unroll
          for (int g = 0; g < 2; ++g)
#pragma unroll
            for (int c = 0; c < 8; ++c)
              xv[it][g][c] = p0[(size_t)(g * 8 + c) * 4096];
        } else {
#pragma unroll
          for (int g = 0; g < 2; ++g)
#pragma unroll
            for (int c = 0; c < 8; ++c) xv[it][g][c] = 0.f;
        }
      }
    }
  };

  auto write_x = [&](float (&xv)[3][2][8], f16* xsub) {
    f16* d = xsub + p_st * 4760 + idx_st * 16;
#pragma unroll
    for (int it = 0; it < 3; ++it) {
      const int r = rru + it * 4;
      if (r < 9) {
#pragma unroll
        for (int g = 0; g < 2; ++g) {
          half8 v;
#pragma unroll
          for (int c = 0; c < 8; ++c) v[c] = (f16)xv[it][g][c];
          *(half8*)&d[r * 528 + (g ^ gx) * 8] = v;
        }
      }
    }
  };

  // compute one 32-ci pair: 2 sub-tiles x 9 taps x 4 MFMA = 72 MFMA
  auto compute = [&](const f16* Abc, const f16* xcur) {
    __builtin_amdgcn_s_setprio(1);
#pragma unroll
    for (int s = 0; s < 2; ++s) {
      const f16* As  = Abc + s * 18432;
      const f16* xss = xcur + s * SUBT;
      const f16* Be  = xss + wn * 2112 + ml * 16 + (k0 ^ (ml & 8));  // even plane
      const f16* Bo1 = Be + 4760;                                    // odd, idx=ml
      const f16* Bo2 = xss + 4760 + wn * 2112 + (ml + 1) * 16 + (k0 ^ ((ml + 1) & 8));
#pragma unroll
      for (int kh = 0; kh < 3; ++kh) {
        half8 a0[3], a1[3];                    // kh-grouped: 24 live A VGPRs
#pragma unroll
        for (int kw = 0; kw < 3; ++kw) {
          a0[kw] = *(const half8*)&As[(kh * 3 + kw) * 2048];
          a1[kw] = *(const half8*)&As[(kh * 3 + kw) * 2048 + 512];
        }
#pragma unroll
        for (int kw = 0; kw < 3; ++kw) {
          const f16* Bp = (kw == 0) ? Bo1 : (kw == 1) ? Be : Bo2;
#pragma unroll
          for (int nj = 0; nj < 2; ++nj) {
            half8 bf = *(const half8*)&Bp[nj * 1056 + kh * 528];
            acc[0][nj] = __builtin_amdgcn_mfma_f32_32x32x16_f16(a0[kw], bf, acc[0][nj], 0, 0, 0);
            acc[1][nj] = __builtin_amdgcn_mfma_f32_32x32x16_f16(a1[kw], bf, acc[1][nj], 0, 0, 0);
          }
        }
      }
    }
    __builtin_amdgcn_s_setprio(0);
  };

  // zero the odd-plane pad column (iw=-1 -> idx 0) of all 4 sub-tiles, once
  if (t < 144) {
    const int r = t >> 4, ci = t & 15;
#pragma unroll
    for (int sb = 0; sb < 4; ++sb)
      xs[sb * SUBT + 4760 + r * 528 + ci] = (f16)0.f;
  }

  // prologue: stage pair 0; issue pair-1 loads
  load_x(xva, 0);
  load_x(xvb, 1);
  write_x(xva, xs0);
  write_x(xvb, xs0 + SUBT);
  load_x(xva, 2);
  load_x(xvb, 3);
  __syncthreads();   // single full drain, outside the hot loop

  const f16* Abc = AbL;
  f16* curp = xs0;
  f16* othp = xs1;
#pragma unroll 1
  for (int pi = 0; pi < 8; ++pi) {
    compute(Abc, curp);                 // LDS B + global A, 72 MFMA
    Abc += 36864;
    if (pi < 7) {
      write_x(xva, othp);               // pair pi+1 (loads issued last iter)
      write_x(xvb, othp + SUBT);
      if (pi < 6) {
        load_x(xva, 2 * pi + 4);
        load_x(xvb, 2 * pi + 5);
      }
      wg_barrier();                     // publish buffer; loads stay in flight
      f16* tm = curp; curp = othp; othp = tm;
    }
  }

  // ---- epilogue: C/D col=lane&31 (=ow), row=(reg&3)+8*(reg>>2)+4*(lane>>5) ----
  const int col = ml;
  const int rowbase = (lane >> 5) * 4;
  float* ob = out + ((size_t)b * COUT + co_t * 128 + wm * 64) * (OH * OW);
#pragma unroll
  for (int mi = 0; mi < 2; ++mi) {
#pragma unroll
    for (int nj = 0; nj < 2; ++nj) {
      const int oh = oh0 + wn * 2 + nj;
#pragma unroll
      for (int r = 0; r < 16; ++r) {
        const int row = mi * 32 + (r & 3) + 8 * (r >> 2) + rowbase;
        ob[(size_t)row * (OH * OW) + oh * OW + col] = acc[mi][nj][r];
      }
    }
  }
}

extern "C" void kernel_launch(void* const* d_in, const int* in_sizes, int n_in,
                              void* d_out, int out_size, void* d_ws, size_t ws_size,
                              hipStream_t stream) {
  const float* x = (const float*)d_in[0];   // [32][256][64][64] fp32
  const float* w = (const float*)d_in[1];   // [256][256][3][3]  fp32
  float* out = (float*)d_out;               // [32][256][32][32] fp32
  f16* rp = (f16*)d_ws;                     // 1.18 MB repacked f16 weights

  repack_w_kernel<<<2304, 256, 0, stream>>>(w, rp);
  conv_mfma_kernel<<<512, 256, 0, stream>>>(x, rp, out);
}